// Round 8
// baseline (241.363 us; speedup 1.0000x reference)
//
#include <hip/hip_runtime.h>
#include <math.h>
#include <stdint.h>

#define HW    112
#define HW2   (112 * 112)
#define NIMG  64
#define CIN   128
#define NKG   2            // split-K groups over input channels
#define ICG   (CIN / NKG)  // 64 ic per group
#define TILEP 2032         // padded LDS slot stride in floats (16B multiple)
#define NSLOT 4
#define NWG   (2 * ICG * 9)  // 1152 weights per group (both oc)

__device__ __forceinline__ float gelu_exact(float v) {
    return 0.5f * v * (1.0f + erff(v * 0.70710678118654752f));
}

// ---------------------------------------------------------------------------
// K1a: partial[kg][n][oc][h][w] = sum over ic-group of conv3x3(x, w1)
// grid (7, 64, 2), block 256. 4-slot rotating LDS pipeline, counted vmcnt
// (steady-state wait vmcnt(6), 8 outstanding), raw s_barrier. Every wave
// issues exactly 2 global_load_lds per stage -> exact vmcnt bookkeeping.
// ---------------------------------------------------------------------------
__global__ __launch_bounds__(256) void k1_partial(
    const float* __restrict__ x, const float* __restrict__ w1,
    float* __restrict__ part) {
    __shared__ __align__(16) float tile[NSLOT][TILEP];
    __shared__ float wlds[NWG];

    const int tid = threadIdx.x;
    const int bx  = blockIdx.x;   // 0..6 h-tiles
    const int n   = blockIdx.y;
    const int kg  = blockIdx.z;
    const int h0  = bx * 16;
    const int icb = kg * ICG;

    const int tx   = tid & 15;
    const int ty   = tid >> 4;
    const int col0 = tx * 7;

    // weights for this group -> LDS: wlds[oc*576 + ic*9 + k]
    for (int j = tid; j < NWG; j += 256) {
        const int oc   = j / (ICG * 9);
        const int rest = j - oc * (ICG * 9);
        wlds[j] = w1[(size_t)oc * CIN * 9 + (size_t)icb * 9 + rest];
    }
    // zero border rows (never overwritten by staging)
    if (bx == 0 && tid < HW) {
#pragma unroll
        for (int s = 0; s < NSLOT; ++s) tile[s][tid] = 0.f;
    }
    if (bx == 6 && tid < HW) {
#pragma unroll
        for (int s = 0; s < NSLOT; ++s) tile[s][17 * HW + tid] = 0.f;
    }

    const int    ldsoff = (bx == 0) ? HW : 0;                 // skip zero row 0
    const int    count4 = (bx == 0 || bx == 6) ? 476 : 504;   // float4s staged
    const size_t srcoff = (bx == 0) ? 0 : (size_t)(h0 - 1) * HW;
    const float* xn = x + ((size_t)n * CIN + icb) * HW2 + srcoff;

    const float lmask = (col0 > 0) ? 1.f : 0.f;
    const float rmask = (col0 + 7 < HW) ? 1.f : 0.f;
    const int   loff  = (col0 > 0) ? -1 : 0;
    const int   roff  = (col0 + 7 < HW) ? 7 : 0;

    float acc0[7] = {0.f, 0.f, 0.f, 0.f, 0.f, 0.f, 0.f};
    float acc1[7] = {0.f, 0.f, 0.f, 0.f, 0.f, 0.f, 0.f};

#define STAGE(CH, SLOT)                                                        \
    do {                                                                       \
        const float* _src = xn + (size_t)(CH) * HW2;                           \
        float* _dst = &tile[(SLOT)][ldsoff];                                   \
        _Pragma("unroll")                                                      \
        for (int _r = 0; _r < 2; ++_r) {                                       \
            const int _i = tid + _r * 256;                                     \
            if (_i < count4)                                                   \
                __builtin_amdgcn_global_load_lds(                              \
                    (const __attribute__((address_space(1))) unsigned int*)(_src + (size_t)_i * 4), \
                    (__attribute__((address_space(3))) unsigned int*)(_dst + _i * 4), \
                    16, 0, 0);                                                 \
        }                                                                      \
    } while (0)

    // prologue: fill 4-deep pipe (8 gload_lds outstanding per wave)
    STAGE(0, 0);
    STAGE(1, 1);
    STAGE(2, 2);
    STAGE(3, 3);
    asm volatile("s_waitcnt lgkmcnt(0)" ::: "memory");  // wlds/zero writes done

    int slot = 0;
#pragma unroll 1
    for (int ic = 0; ic < ICG; ++ic) {
        // wait for this wave's 2 loads of channel `ic` (oldest outstanding)
        if (ic < ICG - 3)       asm volatile("s_waitcnt vmcnt(6)" ::: "memory");
        else if (ic == ICG - 3) asm volatile("s_waitcnt vmcnt(4)" ::: "memory");
        else if (ic == ICG - 2) asm volatile("s_waitcnt vmcnt(2)" ::: "memory");
        else                    asm volatile("s_waitcnt vmcnt(0)" ::: "memory");
        __builtin_amdgcn_s_barrier();           // all waves' shares landed
        __builtin_amdgcn_sched_barrier(0);

        const float* tl  = tile[slot];
        const float* wap = wlds + ic * 9;              // oc = 0
        const float* wbp = wlds + ICG * 9 + ic * 9;    // oc = 1
#pragma unroll
        for (int dr = 0; dr < 3; ++dr) {
            const int base = (ty + dr) * HW + col0;
            float v[9];
            v[0] = tl[base + loff] * lmask;
#pragma unroll
            for (int k = 1; k <= 7; ++k) v[k] = tl[base + (k - 1)];
            v[8] = tl[base + roff] * rmask;
            const float a0 = wap[dr * 3 + 0], a1 = wap[dr * 3 + 1], a2 = wap[dr * 3 + 2];
            const float c0 = wbp[dr * 3 + 0], c1 = wbp[dr * 3 + 1], c2 = wbp[dr * 3 + 2];
#pragma unroll
            for (int j = 0; j < 7; ++j) {
                acc0[j] += a0 * v[j] + a1 * v[j + 1] + a2 * v[j + 2];
                acc1[j] += c0 * v[j] + c1 * v[j + 1] + c2 * v[j + 2];
            }
        }

        asm volatile("s_waitcnt lgkmcnt(0)" ::: "memory");  // own slot reads done
        __builtin_amdgcn_sched_barrier(0);
        __builtin_amdgcn_s_barrier();           // all waves done reading slot
        if (ic + NSLOT < ICG) STAGE(ic + NSLOT, slot);  // refill freed slot
        slot = (slot + 1) & (NSLOT - 1);
    }
#undef STAGE

    const size_t obase = ((size_t)kg * NIMG + n) * 2;
    float* p0 = part + (obase + 0) * HW2 + (size_t)(h0 + ty) * HW + col0;
    float* p1 = part + (obase + 1) * HW2 + (size_t)(h0 + ty) * HW + col0;
#pragma unroll
    for (int j = 0; j < 7; ++j) { p0[j] = acc0[j]; p1[j] = acc1[j]; }
}

// K1b: g = gelu(part[0] + part[1] + bias)
__global__ __launch_bounds__(256) void k1b_reduce_gelu(
    const float* __restrict__ part, const float* __restrict__ b1,
    float* __restrict__ g, int total4) {
    int idx = blockIdx.x * blockDim.x + threadIdx.x;
    if (idx >= total4) return;
    const size_t stride = (size_t)NIMG * 2 * HW2;
    const size_t e = (size_t)idx * 4;
    const int oc = (int)((e / HW2) & 1);
    float4 s = *reinterpret_cast<const float4*>(part + e);
#pragma unroll
    for (int kg = 1; kg < NKG; ++kg) {
        const float4 p = *reinterpret_cast<const float4*>(part + kg * stride + e);
        s.x += p.x; s.y += p.y; s.z += p.z; s.w += p.w;
    }
    const float bb = b1[oc];
    float4 o;
    o.x = gelu_exact(s.x + bb);
    o.y = gelu_exact(s.y + bb);
    o.z = gelu_exact(s.z + bb);
    o.w = gelu_exact(s.w + bb);
    *reinterpret_cast<float4*>(g + e) = o;
}

// Fallback monolithic K1 (only if ws too small)
__global__ __launch_bounds__(448) void k1_conv1_gelu(
    const float* __restrict__ x, const float* __restrict__ w1,
    const float* __restrict__ b1, float* __restrict__ g) {
    const int n  = blockIdx.y;
    const int h  = blockIdx.x * 16 + threadIdx.y;
    const int w0 = threadIdx.x * 4;
    float acc0[4], acc1[4];
    const float bb0 = b1[0], bb1 = b1[1];
#pragma unroll
    for (int j = 0; j < 4; ++j) { acc0[j] = bb0; acc1[j] = bb1; }
    const float* xn = x + (size_t)n * CIN * HW2;
#pragma unroll 4
    for (int ic = 0; ic < CIN; ++ic) {
        const float* xc = xn + (size_t)ic * HW2;
        const float* wa = w1 + ic * 9;
        const float* wb = w1 + (CIN + ic) * 9;
#pragma unroll
        for (int dh = -1; dh <= 1; ++dh) {
            const int hh = h + dh;
            if (hh < 0 || hh >= HW) continue;
            const float* xr = xc + hh * HW;
            const float4 c4  = *reinterpret_cast<const float4*>(xr + w0);
            const float left  = (w0 > 0)      ? xr[w0 - 1] : 0.0f;
            const float right = (w0 + 4 < HW) ? xr[w0 + 4] : 0.0f;
            const float v0 = left, v1 = c4.x, v2 = c4.y, v3 = c4.z, v4 = c4.w, v5 = right;
            const int r = (dh + 1) * 3;
            const float a0 = wa[r], a1 = wa[r + 1], a2 = wa[r + 2];
            const float c0 = wb[r], c1 = wb[r + 1], c2 = wb[r + 2];
            acc0[0] += a0 * v0 + a1 * v1 + a2 * v2;
            acc0[1] += a0 * v1 + a1 * v2 + a2 * v3;
            acc0[2] += a0 * v2 + a1 * v3 + a2 * v4;
            acc0[3] += a0 * v3 + a1 * v4 + a2 * v5;
            acc1[0] += c0 * v0 + c1 * v1 + c2 * v2;
            acc1[1] += c0 * v1 + c1 * v2 + c2 * v3;
            acc1[2] += c0 * v2 + c1 * v3 + c2 * v4;
            acc1[3] += c0 * v3 + c1 * v4 + c2 * v5;
        }
    }
    float4 o0, o1;
    o0.x = gelu_exact(acc0[0]); o0.y = gelu_exact(acc0[1]);
    o0.z = gelu_exact(acc0[2]); o0.w = gelu_exact(acc0[3]);
    o1.x = gelu_exact(acc1[0]); o1.y = gelu_exact(acc1[1]);
    o1.z = gelu_exact(acc1[2]); o1.w = gelu_exact(acc1[3]);
    float* g0 = g + (size_t)(n * 2 + 0) * HW2 + h * HW + w0;
    float* g1 = g + (size_t)(n * 2 + 1) * HW2 + h * HW + w0;
    *reinterpret_cast<float4*>(g0) = o0;
    *reinterpret_cast<float4*>(g1) = o1;
}

// ---------------------------------------------------------------------------
// K23: fused conv2 + sigmoid + blend + transpose.
// grid (7, 64), block 448. Stage 18-row g-tile (2ch) in LDS, each thread
// computes s0 for its own 4 px (same mapping as blend), then streams the
// 64-channel blend: out[b][c][t][h][w] = s*x1 + (1-s)*x2. Barrier-free loop.
// ---------------------------------------------------------------------------
__global__ __launch_bounds__(448) void k23_conv2_blend(
    const float* __restrict__ g, const float* __restrict__ w2,
    const float* __restrict__ b2, const float* __restrict__ x,
    float* __restrict__ out) {
    __shared__ __align__(16) float gs[2][18 * HW];  // tile row r <-> global h0-1+r

    const int tid = threadIdx.x;
    const int bx  = blockIdx.x;
    const int n   = blockIdx.y;
    const int h0  = bx * 16;

    // stage g-tile: 1008 float4s, zero rows outside the image
    for (int i = tid; i < 1008; i += 448) {
        const int ch  = i / 504;
        const int rem = i - ch * 504;
        const int r   = rem / 28;
        const int c4  = rem - r * 28;
        const int hh  = h0 - 1 + r;
        float4 v = make_float4(0.f, 0.f, 0.f, 0.f);
        if (hh >= 0 && hh < HW)
            v = *reinterpret_cast<const float4*>(
                g + ((size_t)(n * 2 + ch) * HW + hh) * HW + c4 * 4);
        *reinterpret_cast<float4*>(&gs[ch][r * HW + c4 * 4]) = v;
    }
    __syncthreads();

    // conv2 + sigmoid for this thread's 4 px
    const int row  = tid / 28;          // 0..15
    const int col0 = (tid - row * 28) * 4;
    const float lm = (col0 > 0) ? 1.f : 0.f;
    const float rm = (col0 + 4 < HW) ? 1.f : 0.f;
    const int   lo = (col0 > 0) ? -1 : 0;
    const int   ro = (col0 + 4 < HW) ? 1 : 0;   // right halo = col0+4 (base+3+1)

    float accA[4], accB[4];
    const float bb0 = b2[0], bb1 = b2[1];
#pragma unroll
    for (int j = 0; j < 4; ++j) { accA[j] = bb0; accB[j] = bb1; }

#pragma unroll
    for (int ch = 0; ch < 2; ++ch) {
        const float* wa = w2 + ch * 9;        // oc = 0
        const float* wb = w2 + (2 + ch) * 9;  // oc = 1
#pragma unroll
        for (int dr = 0; dr < 3; ++dr) {
            const int base = (row + dr) * HW + col0;  // tile row row+dr <-> h0+row-1+dr
            const float4 c4 = *reinterpret_cast<const float4*>(&gs[ch][base]);
            const float v0 = gs[ch][base + lo] * lm;
            const float v5 = gs[ch][base + 3 + ro] * rm;
            const float v1 = c4.x, v2 = c4.y, v3 = c4.z, v4 = c4.w;
            const float a0 = wa[dr * 3], a1 = wa[dr * 3 + 1], a2 = wa[dr * 3 + 2];
            const float c0 = wb[dr * 3], c1 = wb[dr * 3 + 1], c2 = wb[dr * 3 + 2];
            accA[0] += a0 * v0 + a1 * v1 + a2 * v2;
            accA[1] += a0 * v1 + a1 * v2 + a2 * v3;
            accA[2] += a0 * v2 + a1 * v3 + a2 * v4;
            accA[3] += a0 * v3 + a1 * v4 + a2 * v5;
            accB[0] += c0 * v0 + c1 * v1 + c2 * v2;
            accB[1] += c0 * v1 + c1 * v2 + c2 * v3;
            accB[2] += c0 * v2 + c1 * v3 + c2 * v4;
            accB[3] += c0 * v3 + c1 * v4 + c2 * v5;
        }
    }

    float4 s;
    s.x = 1.0f / (1.0f + expf(gelu_exact(accB[0]) - gelu_exact(accA[0])));
    s.y = 1.0f / (1.0f + expf(gelu_exact(accB[1]) - gelu_exact(accA[1])));
    s.z = 1.0f / (1.0f + expf(gelu_exact(accB[2]) - gelu_exact(accA[2])));
    s.w = 1.0f / (1.0f + expf(gelu_exact(accB[3]) - gelu_exact(accA[3])));

    // blend: 64 channel-pairs, fully coalesced (448 thr x 16B = one row-block)
    const int b = n >> 4, t = n & 15;
    const size_t px = (size_t)(h0 + row) * HW + col0;
    const float* x1p = x + ((size_t)n * CIN) * HW2 + px;
    const float* x2p = x1p + (size_t)64 * HW2;
    float* op = out + (((size_t)(b * 64) * 16 + t) * HW2) + px;
#pragma unroll 4
    for (int c = 0; c < 64; ++c) {
        const float4 x1 = *reinterpret_cast<const float4*>(x1p);
        const float4 x2 = *reinterpret_cast<const float4*>(x2p);
        float4 o;
        o.x = s.x * x1.x + (1.0f - s.x) * x2.x;
        o.y = s.y * x1.y + (1.0f - s.y) * x2.y;
        o.z = s.z * x1.z + (1.0f - s.z) * x2.z;
        o.w = s.w * x1.w + (1.0f - s.w) * x2.w;
        *reinterpret_cast<float4*>(op) = o;
        x1p += HW2; x2p += HW2; op += (size_t)16 * HW2;
    }
}

extern "C" void kernel_launch(void* const* d_in, const int* in_sizes, int n_in,
                              void* d_out, int out_size, void* d_ws, size_t ws_size,
                              hipStream_t stream) {
    const float* x  = (const float*)d_in[0];
    const float* w1 = (const float*)d_in[1];
    const float* b1 = (const float*)d_in[2];
    const float* w2 = (const float*)d_in[3];
    const float* b2 = (const float*)d_in[4];
    float* out = (float*)d_out;

    const size_t partF = (size_t)NKG * NIMG * 2 * HW2;  // 12.8 MB
    const size_t gF    = (size_t)NIMG * 2 * HW2;        //  6.4 MB
    const size_t need  = (partF + gF) * sizeof(float);

    dim3 grd(7, NIMG);

    float* g;
    if (ws_size >= need) {
        float* part = (float*)d_ws;
        g = part + partF;
        dim3 grdp(7, NIMG, NKG);
        k1_partial<<<grdp, 256, 0, stream>>>(x, w1, part);
        const int total4g = (int)(gF / 4);
        k1b_reduce_gelu<<<(total4g + 255) / 256, 256, 0, stream>>>(part, b1, g, total4g);
    } else {
        g = (float*)d_ws;
        dim3 blk(28, 16);
        k1_conv1_gelu<<<grd, blk, 0, stream>>>(x, w1, b1, g);
    }

    k23_conv2_blend<<<grd, 448, 0, stream>>>(g, w2, b2, x, out);
}

// Round 10
// 217.939 us; speedup vs baseline: 1.1075x; 1.1075x over previous
//
#include <hip/hip_runtime.h>
#include <math.h>
#include <stdint.h>

#define HW    112
#define HW2   (112 * 112)
#define NIMG  64
#define CIN   128
#define NKG   8            // split-K groups over input channels
#define ICG   (CIN / NKG)  // 16 ic per group
#define TILEP 2032         // padded LDS slot stride in floats (16B multiple)
#define NSLOT 3
#define NWG   (2 * ICG * 9)  // 288 weights per group (both oc)

__device__ __forceinline__ float gelu_exact(float v) {
    return 0.5f * v * (1.0f + erff(v * 0.70710678118654752f));
}

// ---------------------------------------------------------------------------
// K1a: partial[kg][n][oc][h][w] = sum over 16-ch group of conv3x3(x, w1)
// grid (7, 64, 8) = 3584 blocks (14/CU, perfectly balanced), block 256.
// 3-slot rotating LDS pipeline, counted vmcnt (steady wait vmcnt(4), lead 2),
// raw s_barrier. Every wave issues exactly 2 global_load_lds per stage.
// LDS 25.5 KB -> 6 resident blocks/CU = 24 waves/CU (TLP + pipeline).
// ---------------------------------------------------------------------------
__global__ __launch_bounds__(256) void k1_partial(
    const float* __restrict__ x, const float* __restrict__ w1,
    float* __restrict__ part) {
    __shared__ __align__(16) float tile[NSLOT][TILEP];
    __shared__ float wlds[NWG];

    const int tid = threadIdx.x;
    const int bx  = blockIdx.x;   // 0..6 h-tiles
    const int n   = blockIdx.y;
    const int kg  = blockIdx.z;
    const int h0  = bx * 16;
    const int icb = kg * ICG;

    const int tx   = tid & 15;
    const int ty   = tid >> 4;
    const int col0 = tx * 7;

    // weights for this group -> LDS: wlds[oc*ICG*9 + ic*9 + k]  (NWG=288 > 256!)
    for (int j = tid; j < NWG; j += 256) {
        const int oc   = j / (ICG * 9);
        const int rest = j - oc * (ICG * 9);
        wlds[j] = w1[(size_t)oc * CIN * 9 + (size_t)icb * 9 + rest];
    }
    // zero border rows (never overwritten by staging)
    if (bx == 0 && tid < HW) {
#pragma unroll
        for (int s = 0; s < NSLOT; ++s) tile[s][tid] = 0.f;
    }
    if (bx == 6 && tid < HW) {
#pragma unroll
        for (int s = 0; s < NSLOT; ++s) tile[s][17 * HW + tid] = 0.f;
    }

    const int    ldsoff = (bx == 0) ? HW : 0;                 // skip zero row 0
    const int    count4 = (bx == 0 || bx == 6) ? 476 : 504;   // float4s staged
    const size_t srcoff = (bx == 0) ? 0 : (size_t)(h0 - 1) * HW;
    const float* xn = x + ((size_t)n * CIN + icb) * HW2 + srcoff;

    const float lmask = (col0 > 0) ? 1.f : 0.f;
    const float rmask = (col0 + 7 < HW) ? 1.f : 0.f;
    const int   loff  = (col0 > 0) ? -1 : 0;
    const int   roff  = (col0 + 7 < HW) ? 7 : 0;

    float acc0[7] = {0.f, 0.f, 0.f, 0.f, 0.f, 0.f, 0.f};
    float acc1[7] = {0.f, 0.f, 0.f, 0.f, 0.f, 0.f, 0.f};

#define STAGE(CH, SLOT)                                                        \
    do {                                                                       \
        const float* _src = xn + (size_t)(CH) * HW2;                           \
        float* _dst = &tile[(SLOT)][ldsoff];                                   \
        _Pragma("unroll")                                                      \
        for (int _r = 0; _r < 2; ++_r) {                                       \
            const int _i = tid + _r * 256;                                     \
            if (_i < count4)                                                   \
                __builtin_amdgcn_global_load_lds(                              \
                    (const __attribute__((address_space(1))) unsigned int*)(_src + (size_t)_i * 4), \
                    (__attribute__((address_space(3))) unsigned int*)(_dst + _i * 4), \
                    16, 0, 0);                                                 \
        }                                                                      \
    } while (0)

    // prologue: fill 3-deep pipe (6 gload_lds outstanding per wave)
    STAGE(0, 0);
    STAGE(1, 1);
    STAGE(2, 2);
    asm volatile("s_waitcnt lgkmcnt(0)" ::: "memory");  // own wlds/zero writes drained

    int slot = 0;
#pragma unroll 1
    for (int ic = 0; ic < ICG; ++ic) {
        // wait for this wave's 2 loads of channel `ic` (oldest outstanding)
        if (ic < ICG - 2)       asm volatile("s_waitcnt vmcnt(4)" ::: "memory");
        else if (ic == ICG - 2) asm volatile("s_waitcnt vmcnt(2)" ::: "memory");
        else                    asm volatile("s_waitcnt vmcnt(0)" ::: "memory");
        __builtin_amdgcn_s_barrier();           // all waves' shares landed
        __builtin_amdgcn_sched_barrier(0);

        const float* tl  = tile[slot];
        const float* wap = wlds + ic * 9;              // oc = 0
        const float* wbp = wlds + ICG * 9 + ic * 9;    // oc = 1
#pragma unroll
        for (int dr = 0; dr < 3; ++dr) {
            const int base = (ty + dr) * HW + col0;
            float v[9];
            v[0] = tl[base + loff] * lmask;
#pragma unroll
            for (int k = 1; k <= 7; ++k) v[k] = tl[base + (k - 1)];
            v[8] = tl[base + roff] * rmask;
            const float a0 = wap[dr * 3 + 0], a1 = wap[dr * 3 + 1], a2 = wap[dr * 3 + 2];
            const float c0 = wbp[dr * 3 + 0], c1 = wbp[dr * 3 + 1], c2 = wbp[dr * 3 + 2];
#pragma unroll
            for (int j = 0; j < 7; ++j) {
                acc0[j] += a0 * v[j] + a1 * v[j + 1] + a2 * v[j + 2];
                acc1[j] += c0 * v[j] + c1 * v[j + 1] + c2 * v[j + 2];
            }
        }

        asm volatile("s_waitcnt lgkmcnt(0)" ::: "memory");  // own slot reads retired
        __builtin_amdgcn_sched_barrier(0);
        __builtin_amdgcn_s_barrier();           // all waves done reading slot
        if (ic + NSLOT < ICG) STAGE(ic + NSLOT, slot);  // refill freed slot
        slot = (slot == NSLOT - 1) ? 0 : slot + 1;
    }
#undef STAGE

    const size_t obase = ((size_t)kg * NIMG + n) * 2;
    float* p0 = part + (obase + 0) * HW2 + (size_t)(h0 + ty) * HW + col0;
    float* p1 = part + (obase + 1) * HW2 + (size_t)(h0 + ty) * HW + col0;
#pragma unroll
    for (int j = 0; j < 7; ++j) { p0[j] = acc0[j]; p1[j] = acc1[j]; }
}

// ---------------------------------------------------------------------------
// K2f: fused reduce(8 partials)+bias+GELU staging -> conv2 -> sigmoid -> s0.
// grid (7, 64), block 448. g is never materialized in HBM.
// ---------------------------------------------------------------------------
__global__ __launch_bounds__(448) void k2f_reduce_conv2(
    const float* __restrict__ part, const float* __restrict__ b1,
    const float* __restrict__ w2, const float* __restrict__ b2,
    float* __restrict__ s0) {
    __shared__ __align__(16) float gs[2][18 * HW];  // tile row r <-> global h0-1+r

    const int tid = threadIdx.x;
    const int bx  = blockIdx.x;
    const int n   = blockIdx.y;
    const int h0  = bx * 16;
    const size_t kstride = (size_t)NIMG * 2 * HW2;

    // stage g-tile: sum 8 partials + bias, gelu; zero rows outside image
    for (int i = tid; i < 1008; i += 448) {
        const int ch  = i / 504;
        const int rem = i - ch * 504;
        const int r   = rem / 28;
        const int c4  = rem - r * 28;
        const int hh  = h0 - 1 + r;
        float4 v = make_float4(0.f, 0.f, 0.f, 0.f);
        if (hh >= 0 && hh < HW) {
            const float* p = part + ((size_t)n * 2 + ch) * HW2 + (size_t)hh * HW + c4 * 4;
            float4 a = *reinterpret_cast<const float4*>(p);
#pragma unroll
            for (int kg = 1; kg < NKG; ++kg) {
                const float4 q = *reinterpret_cast<const float4*>(p + kg * kstride);
                a.x += q.x; a.y += q.y; a.z += q.z; a.w += q.w;
            }
            const float bb = b1[ch];
            v.x = gelu_exact(a.x + bb);
            v.y = gelu_exact(a.y + bb);
            v.z = gelu_exact(a.z + bb);
            v.w = gelu_exact(a.w + bb);
        }
        *reinterpret_cast<float4*>(&gs[ch][r * HW + c4 * 4]) = v;
    }
    __syncthreads();

    // conv2 + sigmoid for this thread's 4 px
    const int row  = tid / 28;          // 0..15
    const int col0 = (tid - row * 28) * 4;
    const float lm = (col0 > 0) ? 1.f : 0.f;
    const float rm = (col0 + 4 < HW) ? 1.f : 0.f;
    const int   lo = (col0 > 0) ? -1 : 0;
    const int   ro = (col0 + 4 < HW) ? 1 : 0;   // right halo = gs[base+4]

    float accA[4], accB[4];
    const float bb0 = b2[0], bb1 = b2[1];
#pragma unroll
    for (int j = 0; j < 4; ++j) { accA[j] = bb0; accB[j] = bb1; }

#pragma unroll
    for (int ch = 0; ch < 2; ++ch) {
        const float* wa = w2 + ch * 9;        // oc = 0
        const float* wb = w2 + (2 + ch) * 9;  // oc = 1
#pragma unroll
        for (int dr = 0; dr < 3; ++dr) {
            const int base = (row + dr) * HW + col0;
            const float4 c4 = *reinterpret_cast<const float4*>(&gs[ch][base]);
            const float v0 = gs[ch][base + lo] * lm;
            const float v5 = gs[ch][base + 3 + ro] * rm;
            const float v1 = c4.x, v2 = c4.y, v3 = c4.z, v4 = c4.w;
            const float a0 = wa[dr * 3], a1 = wa[dr * 3 + 1], a2 = wa[dr * 3 + 2];
            const float c0 = wb[dr * 3], c1 = wb[dr * 3 + 1], c2 = wb[dr * 3 + 2];
            accA[0] += a0 * v0 + a1 * v1 + a2 * v2;
            accA[1] += a0 * v1 + a1 * v2 + a2 * v3;
            accA[2] += a0 * v2 + a1 * v3 + a2 * v4;
            accA[3] += a0 * v3 + a1 * v4 + a2 * v5;
            accB[0] += c0 * v0 + c1 * v1 + c2 * v2;
            accB[1] += c0 * v1 + c1 * v2 + c2 * v3;
            accB[2] += c0 * v2 + c1 * v3 + c2 * v4;
            accB[3] += c0 * v3 + c1 * v4 + c2 * v5;
        }
    }

    float4 o;
    o.x = 1.0f / (1.0f + expf(gelu_exact(accB[0]) - gelu_exact(accA[0])));
    o.y = 1.0f / (1.0f + expf(gelu_exact(accB[1]) - gelu_exact(accA[1])));
    o.z = 1.0f / (1.0f + expf(gelu_exact(accB[2]) - gelu_exact(accA[2])));
    o.w = 1.0f / (1.0f + expf(gelu_exact(accB[3]) - gelu_exact(accA[3])));
    *reinterpret_cast<float4*>(s0 + (size_t)n * HW2 + (size_t)(h0 + row) * HW + col0) = o;
}

// ---------------------------------------------------------------------------
// Fallback path (only if ws too small): monolithic k1 -> g, then k2 -> s0
// ---------------------------------------------------------------------------
__global__ __launch_bounds__(448) void k1_conv1_gelu(
    const float* __restrict__ x, const float* __restrict__ w1,
    const float* __restrict__ b1, float* __restrict__ g) {
    const int n  = blockIdx.y;
    const int h  = blockIdx.x * 16 + threadIdx.y;
    const int w0 = threadIdx.x * 4;
    float acc0[4], acc1[4];
    const float bb0 = b1[0], bb1 = b1[1];
#pragma unroll
    for (int j = 0; j < 4; ++j) { acc0[j] = bb0; acc1[j] = bb1; }
    const float* xn = x + (size_t)n * CIN * HW2;
#pragma unroll 4
    for (int ic = 0; ic < CIN; ++ic) {
        const float* xc = xn + (size_t)ic * HW2;
        const float* wa = w1 + ic * 9;
        const float* wb = w1 + (CIN + ic) * 9;
#pragma unroll
        for (int dh = -1; dh <= 1; ++dh) {
            const int hh = h + dh;
            if (hh < 0 || hh >= HW) continue;
            const float* xr = xc + hh * HW;
            const float4 c4  = *reinterpret_cast<const float4*>(xr + w0);
            const float left  = (w0 > 0)      ? xr[w0 - 1] : 0.0f;
            const float right = (w0 + 4 < HW) ? xr[w0 + 4] : 0.0f;
            const float v0 = left, v1 = c4.x, v2 = c4.y, v3 = c4.z, v4 = c4.w, v5 = right;
            const int r = (dh + 1) * 3;
            const float a0 = wa[r], a1 = wa[r + 1], a2 = wa[r + 2];
            const float c0 = wb[r], c1 = wb[r + 1], c2 = wb[r + 2];
            acc0[0] += a0 * v0 + a1 * v1 + a2 * v2;
            acc0[1] += a0 * v1 + a1 * v2 + a2 * v3;
            acc0[2] += a0 * v2 + a1 * v3 + a2 * v4;
            acc0[3] += a0 * v3 + a1 * v4 + a2 * v5;
            acc1[0] += c0 * v0 + c1 * v1 + c2 * v2;
            acc1[1] += c0 * v1 + c1 * v2 + c2 * v3;
            acc1[2] += c0 * v2 + c1 * v3 + c2 * v4;
            acc1[3] += c0 * v3 + c1 * v4 + c2 * v5;
        }
    }
    float4 o0, o1;
    o0.x = gelu_exact(acc0[0]); o0.y = gelu_exact(acc0[1]);
    o0.z = gelu_exact(acc0[2]); o0.w = gelu_exact(acc0[3]);
    o1.x = gelu_exact(acc1[0]); o1.y = gelu_exact(acc1[1]);
    o1.z = gelu_exact(acc1[2]); o1.w = gelu_exact(acc1[3]);
    float* g0 = g + (size_t)(n * 2 + 0) * HW2 + h * HW + w0;
    float* g1 = g + (size_t)(n * 2 + 1) * HW2 + h * HW + w0;
    *reinterpret_cast<float4*>(g0) = o0;
    *reinterpret_cast<float4*>(g1) = o1;
}

__global__ __launch_bounds__(448) void k2_conv2_softmax(
    const float* __restrict__ g, const float* __restrict__ w2,
    const float* __restrict__ b2, float* __restrict__ s0) {
    const int n  = blockIdx.y;
    const int h  = blockIdx.x * 16 + threadIdx.y;
    const int w0 = threadIdx.x * 4;
    float accA[4], accB[4];
    const float bb0 = b2[0], bb1 = b2[1];
#pragma unroll
    for (int j = 0; j < 4; ++j) { accA[j] = bb0; accB[j] = bb1; }
#pragma unroll
    for (int c = 0; c < 2; ++c) {
        const float* gc = g + (size_t)(n * 2 + c) * HW2;
        const float* wa = w2 + c * 9;
        const float* wb = w2 + (2 + c) * 9;
#pragma unroll
        for (int dh = -1; dh <= 1; ++dh) {
            const int hh = h + dh;
            if (hh < 0 || hh >= HW) continue;
            const float* gr = gc + hh * HW;
            const float4 c4  = *reinterpret_cast<const float4*>(gr + w0);
            const float left  = (w0 > 0)      ? gr[w0 - 1] : 0.0f;
            const float right = (w0 + 4 < HW) ? gr[w0 + 4] : 0.0f;
            const float v0 = left, v1 = c4.x, v2 = c4.y, v3 = c4.z, v4 = c4.w, v5 = right;
            const int r = (dh + 1) * 3;
            const float a0 = wa[r], a1 = wa[r + 1], a2 = wa[r + 2];
            const float c0 = wb[r], c1 = wb[r + 1], c2 = wb[r + 2];
            accA[0] += a0 * v0 + a1 * v1 + a2 * v2;
            accA[1] += a0 * v1 + a1 * v2 + a2 * v3;
            accA[2] += a0 * v2 + a1 * v3 + a2 * v4;
            accA[3] += a0 * v3 + a1 * v4 + a2 * v5;
            accB[0] += c0 * v0 + c1 * v1 + c2 * v2;
            accB[1] += c0 * v1 + c1 * v2 + c2 * v3;
            accB[2] += c0 * v2 + c1 * v3 + c2 * v4;
            accB[3] += c0 * v3 + c1 * v4 + c2 * v5;
        }
    }
    float4 o;
    o.x = 1.0f / (1.0f + expf(gelu_exact(accB[0]) - gelu_exact(accA[0])));
    o.y = 1.0f / (1.0f + expf(gelu_exact(accB[1]) - gelu_exact(accA[1])));
    o.z = 1.0f / (1.0f + expf(gelu_exact(accB[2]) - gelu_exact(accA[2])));
    o.w = 1.0f / (1.0f + expf(gelu_exact(accB[3]) - gelu_exact(accA[3])));
    *reinterpret_cast<float4*>(s0 + (size_t)n * HW2 + h * HW + w0) = o;
}

// K3: out[b][c][t][h][w] = s0*x1 + (1-s0)*x2 — flat balanced grid
__global__ __launch_bounds__(256) void k3_blend(
    const float* __restrict__ x, const float* __restrict__ s0,
    float* __restrict__ out, int total4) {
    int idx = blockIdx.x * blockDim.x + threadIdx.x;
    if (idx >= total4) return;
    const int W4 = HW / 4;
    int w4  = idx % W4;
    int tmp = idx / W4;
    int h   = tmp % HW; tmp /= HW;
    int t   = tmp % 16; tmp /= 16;
    int c   = tmp % 64;
    int b   = tmp / 64;
    const int n = b * 16 + t;

    const size_t px = (size_t)h * HW + w4 * 4;
    const float4 x1 = *reinterpret_cast<const float4*>(x + (size_t)(n * CIN + c)      * HW2 + px);
    const float4 x2 = *reinterpret_cast<const float4*>(x + (size_t)(n * CIN + c + 64) * HW2 + px);
    const float4 s  = *reinterpret_cast<const float4*>(s0 + (size_t)n * HW2 + px);

    float4 o;
    o.x = s.x * x1.x + (1.0f - s.x) * x2.x;
    o.y = s.y * x1.y + (1.0f - s.y) * x2.y;
    o.z = s.z * x1.z + (1.0f - s.z) * x2.z;
    o.w = s.w * x1.w + (1.0f - s.w) * x2.w;
    *reinterpret_cast<float4*>(out + (size_t)idx * 4) = o;
}

extern "C" void kernel_launch(void* const* d_in, const int* in_sizes, int n_in,
                              void* d_out, int out_size, void* d_ws, size_t ws_size,
                              hipStream_t stream) {
    const float* x  = (const float*)d_in[0];
    const float* w1 = (const float*)d_in[1];
    const float* b1 = (const float*)d_in[2];
    const float* w2 = (const float*)d_in[3];
    const float* b2 = (const float*)d_in[4];
    float* out = (float*)d_out;

    const size_t partF = (size_t)NKG * NIMG * 2 * HW2;  // 51.4 MB
    const size_t gF    = (size_t)NIMG * 2 * HW2;        //  6.4 MB
    const size_t s0F   = (size_t)NIMG * HW2;            //  3.2 MB
    const size_t need  = (partF + s0F) * sizeof(float);

    dim3 grd(7, NIMG);
    float* s0;

    if (ws_size >= need) {
        float* part = (float*)d_ws;
        s0 = part + partF;
        dim3 grdp(7, NIMG, NKG);
        k1_partial<<<grdp, 256, 0, stream>>>(x, w1, part);
        k2f_reduce_conv2<<<grd, 448, 0, stream>>>(part, b1, w2, b2, s0);
    } else {
        float* g = (float*)d_ws;
        s0 = g + gF;
        dim3 blk(28, 16);
        k1_conv1_gelu<<<grd, blk, 0, stream>>>(x, w1, b1, g);
        k2_conv2_softmax<<<grd, blk, 0, stream>>>(g, w2, b2, s0);
    }

    const int total4 = 4 * 64 * 16 * HW * (HW / 4);
    k3_blend<<<(total4 + 255) / 256, 256, 0, stream>>>(x, s0, out, total4);
}

// Round 11
// 207.563 us; speedup vs baseline: 1.1628x; 1.0500x over previous
//
#include <hip/hip_runtime.h>
#include <math.h>
#include <stdint.h>

#define HW    112
#define HW2   (112 * 112)
#define NIMG  64
#define CIN   128
#define NKG   4            // split-K groups over input channels
#define ICG   (CIN / NKG)  // 32 ic per group
#define TILEP 2032         // padded LDS slot stride in floats (16B multiple)

__device__ __forceinline__ float gelu_exact(float v) {
    return 0.5f * v * (1.0f + erff(v * 0.70710678118654752f));
}

// ---------------------------------------------------------------------------
// K1a (R5's winning form): partial[kg][n][oc][h][w] = sum over 32-ch group.
// grid (7, 64, 4) = 1792 blocks (7/CU, 28 waves/CU), block 256.
// Double-buffered LDS staging via global_load_lds(16B); prefetch of ic+1
// issued before compute of ic; one __syncthreads per iteration.
// ---------------------------------------------------------------------------
__global__ __launch_bounds__(256) void k1_partial(
    const float* __restrict__ x, const float* __restrict__ w1,
    float* __restrict__ part) {
    __shared__ __align__(16) float tile[2][TILEP];

    const int tid = threadIdx.x;
    const int bx  = blockIdx.x;   // 0..6 h-tiles
    const int n   = blockIdx.y;
    const int kg  = blockIdx.z;
    const int h0  = bx * 16;
    const int icb = kg * ICG;

    const int tx   = tid & 15;
    const int ty   = tid >> 4;
    const int col0 = tx * 7;

    // zero border rows once (never overwritten by staging)
    if (bx == 0 && tid < HW) { tile[0][tid] = 0.f; tile[1][tid] = 0.f; }
    if (bx == 6 && tid < HW) { tile[0][17 * HW + tid] = 0.f; tile[1][17 * HW + tid] = 0.f; }

    const int    ldsoff = (bx == 0) ? HW : 0;                 // skip zero row 0
    const int    count4 = (bx == 0 || bx == 6) ? 476 : 504;   // float4s staged
    const size_t srcoff = (bx == 0) ? 0 : (size_t)(h0 - 1) * HW;
    const float* xn = x + ((size_t)n * CIN + icb) * HW2 + srcoff;

    const float lmask = (col0 > 0) ? 1.f : 0.f;
    const float rmask = (col0 + 7 < HW) ? 1.f : 0.f;
    const int   loff  = (col0 > 0) ? -1 : 0;
    const int   roff  = (col0 + 7 < HW) ? 7 : 0;

    float acc0[7] = {0.f, 0.f, 0.f, 0.f, 0.f, 0.f, 0.f};
    float acc1[7] = {0.f, 0.f, 0.f, 0.f, 0.f, 0.f, 0.f};

    // prologue: stage ic=0 into buf 0
    {
        float* dst = &tile[0][ldsoff];
#pragma unroll
        for (int r = 0; r < 2; ++r) {
            const int i = tid + r * 256;
            if (i < count4)
                __builtin_amdgcn_global_load_lds(
                    (const __attribute__((address_space(1))) unsigned int*)(xn + (size_t)i * 4),
                    (__attribute__((address_space(3))) unsigned int*)(dst + i * 4),
                    16, 0, 0);
        }
    }
    __syncthreads();   // buf0 ready for all waves

    int buf = 0;
    for (int ic = 0; ic < ICG; ++ic) {
        // issue async prefetch of ic+1 into other buffer (flies during compute)
        if (ic + 1 < ICG) {
            const float* src = xn + (size_t)(ic + 1) * HW2;
            float* dst = &tile[buf ^ 1][ldsoff];
#pragma unroll
            for (int r = 0; r < 2; ++r) {
                const int i = tid + r * 256;
                if (i < count4)
                    __builtin_amdgcn_global_load_lds(
                        (const __attribute__((address_space(1))) unsigned int*)(src + (size_t)i * 4),
                        (__attribute__((address_space(3))) unsigned int*)(dst + i * 4),
                        16, 0, 0);
            }
        }

        // compute current channel from LDS (weights via wave-uniform s_loads)
        const float* wa = w1 + (size_t)(icb + ic) * 9;   // oc = 0
        const float* wb = wa + (size_t)CIN * 9;          // oc = 1
        const float* tl = tile[buf];
#pragma unroll
        for (int dr = 0; dr < 3; ++dr) {
            const int base = (ty + dr) * HW + col0;
            float v[9];
            v[0] = tl[base + loff] * lmask;
#pragma unroll
            for (int k = 1; k <= 7; ++k) v[k] = tl[base + (k - 1)];
            v[8] = tl[base + roff] * rmask;
            const float a0 = wa[dr * 3 + 0], a1 = wa[dr * 3 + 1], a2 = wa[dr * 3 + 2];
            const float c0 = wb[dr * 3 + 0], c1 = wb[dr * 3 + 1], c2 = wb[dr * 3 + 2];
#pragma unroll
            for (int j = 0; j < 7; ++j) {
                acc0[j] += a0 * v[j] + a1 * v[j + 1] + a2 * v[j + 2];
                acc1[j] += c0 * v[j] + c1 * v[j + 1] + c2 * v[j + 2];
            }
        }

        __syncthreads();   // prefetch landed; all waves done reading buf
        buf ^= 1;
    }

    const size_t obase = ((size_t)kg * NIMG + n) * 2;
    float* p0 = part + (obase + 0) * HW2 + (size_t)(h0 + ty) * HW + col0;
    float* p1 = part + (obase + 1) * HW2 + (size_t)(h0 + ty) * HW + col0;
#pragma unroll
    for (int j = 0; j < 7; ++j) { p0[j] = acc0[j]; p1[j] = acc1[j]; }
}

// ---------------------------------------------------------------------------
// K2f: fused reduce(4 partials)+bias+GELU staging -> conv2 -> sigmoid -> s0.
// grid (7, 64), block 448. g is never materialized in HBM.
// ---------------------------------------------------------------------------
__global__ __launch_bounds__(448) void k2f_reduce_conv2(
    const float* __restrict__ part, const float* __restrict__ b1,
    const float* __restrict__ w2, const float* __restrict__ b2,
    float* __restrict__ s0) {
    __shared__ __align__(16) float gs[2][18 * HW];  // tile row r <-> global h0-1+r

    const int tid = threadIdx.x;
    const int bx  = blockIdx.x;
    const int n   = blockIdx.y;
    const int h0  = bx * 16;
    const size_t kstride = (size_t)NIMG * 2 * HW2;

    // stage g-tile: sum 4 partials + bias, gelu; zero rows outside image
    for (int i = tid; i < 1008; i += 448) {
        const int ch  = i / 504;
        const int rem = i - ch * 504;
        const int r   = rem / 28;
        const int c4  = rem - r * 28;
        const int hh  = h0 - 1 + r;
        float4 v = make_float4(0.f, 0.f, 0.f, 0.f);
        if (hh >= 0 && hh < HW) {
            const float* p = part + ((size_t)n * 2 + ch) * HW2 + (size_t)hh * HW + c4 * 4;
            float4 a = *reinterpret_cast<const float4*>(p);
#pragma unroll
            for (int kg = 1; kg < NKG; ++kg) {
                const float4 q = *reinterpret_cast<const float4*>(p + kg * kstride);
                a.x += q.x; a.y += q.y; a.z += q.z; a.w += q.w;
            }
            const float bb = b1[ch];
            v.x = gelu_exact(a.x + bb);
            v.y = gelu_exact(a.y + bb);
            v.z = gelu_exact(a.z + bb);
            v.w = gelu_exact(a.w + bb);
        }
        *reinterpret_cast<float4*>(&gs[ch][r * HW + c4 * 4]) = v;
    }
    __syncthreads();

    // conv2 + sigmoid for this thread's 4 px
    const int row  = tid / 28;          // 0..15
    const int col0 = (tid - row * 28) * 4;
    const float lm = (col0 > 0) ? 1.f : 0.f;
    const float rm = (col0 + 4 < HW) ? 1.f : 0.f;
    const int   lo = (col0 > 0) ? -1 : 0;
    const int   ro = (col0 + 4 < HW) ? 1 : 0;   // right halo = gs[base+4]

    float accA[4], accB[4];
    const float bb0 = b2[0], bb1 = b2[1];
#pragma unroll
    for (int j = 0; j < 4; ++j) { accA[j] = bb0; accB[j] = bb1; }

#pragma unroll
    for (int ch = 0; ch < 2; ++ch) {
        const float* wa = w2 + ch * 9;        // oc = 0
        const float* wb = w2 + (2 + ch) * 9;  // oc = 1
#pragma unroll
        for (int dr = 0; dr < 3; ++dr) {
            const int base = (row + dr) * HW + col0;
            const float4 c4 = *reinterpret_cast<const float4*>(&gs[ch][base]);
            const float v0 = gs[ch][base + lo] * lm;
            const float v5 = gs[ch][base + 3 + ro] * rm;
            const float v1 = c4.x, v2 = c4.y, v3 = c4.z, v4 = c4.w;
            const float a0 = wa[dr * 3], a1 = wa[dr * 3 + 1], a2 = wa[dr * 3 + 2];
            const float c0 = wb[dr * 3], c1 = wb[dr * 3 + 1], c2 = wb[dr * 3 + 2];
            accA[0] += a0 * v0 + a1 * v1 + a2 * v2;
            accA[1] += a0 * v1 + a1 * v2 + a2 * v3;
            accA[2] += a0 * v2 + a1 * v3 + a2 * v4;
            accA[3] += a0 * v3 + a1 * v4 + a2 * v5;
            accB[0] += c0 * v0 + c1 * v1 + c2 * v2;
            accB[1] += c0 * v1 + c1 * v2 + c2 * v3;
            accB[2] += c0 * v2 + c1 * v3 + c2 * v4;
            accB[3] += c0 * v3 + c1 * v4 + c2 * v5;
        }
    }

    float4 o;
    o.x = 1.0f / (1.0f + expf(gelu_exact(accB[0]) - gelu_exact(accA[0])));
    o.y = 1.0f / (1.0f + expf(gelu_exact(accB[1]) - gelu_exact(accA[1])));
    o.z = 1.0f / (1.0f + expf(gelu_exact(accB[2]) - gelu_exact(accA[2])));
    o.w = 1.0f / (1.0f + expf(gelu_exact(accB[3]) - gelu_exact(accA[3])));
    *reinterpret_cast<float4*>(s0 + (size_t)n * HW2 + (size_t)(h0 + row) * HW + col0) = o;
}

// ---------------------------------------------------------------------------
// Fallback path (only if ws too small): monolithic k1 -> g, then k2 -> s0
// ---------------------------------------------------------------------------
__global__ __launch_bounds__(448) void k1_conv1_gelu(
    const float* __restrict__ x, const float* __restrict__ w1,
    const float* __restrict__ b1, float* __restrict__ g) {
    const int n  = blockIdx.y;
    const int h  = blockIdx.x * 16 + threadIdx.y;
    const int w0 = threadIdx.x * 4;
    float acc0[4], acc1[4];
    const float bb0 = b1[0], bb1 = b1[1];
#pragma unroll
    for (int j = 0; j < 4; ++j) { acc0[j] = bb0; acc1[j] = bb1; }
    const float* xn = x + (size_t)n * CIN * HW2;
#pragma unroll 4
    for (int ic = 0; ic < CIN; ++ic) {
        const float* xc = xn + (size_t)ic * HW2;
        const float* wa = w1 + ic * 9;
        const float* wb = w1 + (CIN + ic) * 9;
#pragma unroll
        for (int dh = -1; dh <= 1; ++dh) {
            const int hh = h + dh;
            if (hh < 0 || hh >= HW) continue;
            const float* xr = xc + hh * HW;
            const float4 c4  = *reinterpret_cast<const float4*>(xr + w0);
            const float left  = (w0 > 0)      ? xr[w0 - 1] : 0.0f;
            const float right = (w0 + 4 < HW) ? xr[w0 + 4] : 0.0f;
            const float v0 = left, v1 = c4.x, v2 = c4.y, v3 = c4.z, v4 = c4.w, v5 = right;
            const int r = (dh + 1) * 3;
            const float a0 = wa[r], a1 = wa[r + 1], a2 = wa[r + 2];
            const float c0 = wb[r], c1 = wb[r + 1], c2 = wb[r + 2];
            acc0[0] += a0 * v0 + a1 * v1 + a2 * v2;
            acc0[1] += a0 * v1 + a1 * v2 + a2 * v3;
            acc0[2] += a0 * v2 + a1 * v3 + a2 * v4;
            acc0[3] += a0 * v3 + a1 * v4 + a2 * v5;
            acc1[0] += c0 * v0 + c1 * v1 + c2 * v2;
            acc1[1] += c0 * v1 + c1 * v2 + c2 * v3;
            acc1[2] += c0 * v2 + c1 * v3 + c2 * v4;
            acc1[3] += c0 * v3 + c1 * v4 + c2 * v5;
        }
    }
    float4 o0, o1;
    o0.x = gelu_exact(acc0[0]); o0.y = gelu_exact(acc0[1]);
    o0.z = gelu_exact(acc0[2]); o0.w = gelu_exact(acc0[3]);
    o1.x = gelu_exact(acc1[0]); o1.y = gelu_exact(acc1[1]);
    o1.z = gelu_exact(acc1[2]); o1.w = gelu_exact(acc1[3]);
    float* g0 = g + (size_t)(n * 2 + 0) * HW2 + h * HW + w0;
    float* g1 = g + (size_t)(n * 2 + 1) * HW2 + h * HW + w0;
    *reinterpret_cast<float4*>(g0) = o0;
    *reinterpret_cast<float4*>(g1) = o1;
}

__global__ __launch_bounds__(448) void k2_conv2_softmax(
    const float* __restrict__ g, const float* __restrict__ w2,
    const float* __restrict__ b2, float* __restrict__ s0) {
    const int n  = blockIdx.y;
    const int h  = blockIdx.x * 16 + threadIdx.y;
    const int w0 = threadIdx.x * 4;
    float accA[4], accB[4];
    const float bb0 = b2[0], bb1 = b2[1];
#pragma unroll
    for (int j = 0; j < 4; ++j) { accA[j] = bb0; accB[j] = bb1; }
#pragma unroll
    for (int c = 0; c < 2; ++c) {
        const float* gc = g + (size_t)(n * 2 + c) * HW2;
        const float* wa = w2 + c * 9;
        const float* wb = w2 + (2 + c) * 9;
#pragma unroll
        for (int dh = -1; dh <= 1; ++dh) {
            const int hh = h + dh;
            if (hh < 0 || hh >= HW) continue;
            const float* gr = gc + hh * HW;
            const float4 c4  = *reinterpret_cast<const float4*>(gr + w0);
            const float left  = (w0 > 0)      ? gr[w0 - 1] : 0.0f;
            const float right = (w0 + 4 < HW) ? gr[w0 + 4] : 0.0f;
            const float v0 = left, v1 = c4.x, v2 = c4.y, v3 = c4.z, v4 = c4.w, v5 = right;
            const int r = (dh + 1) * 3;
            const float a0 = wa[r], a1 = wa[r + 1], a2 = wa[r + 2];
            const float c0 = wb[r], c1 = wb[r + 1], c2 = wb[r + 2];
            accA[0] += a0 * v0 + a1 * v1 + a2 * v2;
            accA[1] += a0 * v1 + a1 * v2 + a2 * v3;
            accA[2] += a0 * v2 + a1 * v3 + a2 * v4;
            accA[3] += a0 * v3 + a1 * v4 + a2 * v5;
            accB[0] += c0 * v0 + c1 * v1 + c2 * v2;
            accB[1] += c0 * v1 + c1 * v2 + c2 * v3;
            accB[2] += c0 * v2 + c1 * v3 + c2 * v4;
            accB[3] += c0 * v3 + c1 * v4 + c2 * v5;
        }
    }
    float4 o;
    o.x = 1.0f / (1.0f + expf(gelu_exact(accB[0]) - gelu_exact(accA[0])));
    o.y = 1.0f / (1.0f + expf(gelu_exact(accB[1]) - gelu_exact(accA[1])));
    o.z = 1.0f / (1.0f + expf(gelu_exact(accB[2]) - gelu_exact(accA[2])));
    o.w = 1.0f / (1.0f + expf(gelu_exact(accB[3]) - gelu_exact(accA[3])));
    *reinterpret_cast<float4*>(s0 + (size_t)n * HW2 + h * HW + w0) = o;
}

// K3: out[b][c][t][h][w] = s0*x1 + (1-s0)*x2 — flat balanced grid (roofline)
__global__ __launch_bounds__(256) void k3_blend(
    const float* __restrict__ x, const float* __restrict__ s0,
    float* __restrict__ out, int total4) {
    int idx = blockIdx.x * blockDim.x + threadIdx.x;
    if (idx >= total4) return;
    const int W4 = HW / 4;
    int w4  = idx % W4;
    int tmp = idx / W4;
    int h   = tmp % HW; tmp /= HW;
    int t   = tmp % 16; tmp /= 16;
    int c   = tmp % 64;
    int b   = tmp / 64;
    const int n = b * 16 + t;

    const size_t px = (size_t)h * HW + w4 * 4;
    const float4 x1 = *reinterpret_cast<const float4*>(x + (size_t)(n * CIN + c)      * HW2 + px);
    const float4 x2 = *reinterpret_cast<const float4*>(x + (size_t)(n * CIN + c + 64) * HW2 + px);
    const float4 s  = *reinterpret_cast<const float4*>(s0 + (size_t)n * HW2 + px);

    float4 o;
    o.x = s.x * x1.x + (1.0f - s.x) * x2.x;
    o.y = s.y * x1.y + (1.0f - s.y) * x2.y;
    o.z = s.z * x1.z + (1.0f - s.z) * x2.z;
    o.w = s.w * x1.w + (1.0f - s.w) * x2.w;
    *reinterpret_cast<float4*>(out + (size_t)idx * 4) = o;
}

extern "C" void kernel_launch(void* const* d_in, const int* in_sizes, int n_in,
                              void* d_out, int out_size, void* d_ws, size_t ws_size,
                              hipStream_t stream) {
    const float* x  = (const float*)d_in[0];
    const float* w1 = (const float*)d_in[1];
    const float* b1 = (const float*)d_in[2];
    const float* w2 = (const float*)d_in[3];
    const float* b2 = (const float*)d_in[4];
    float* out = (float*)d_out;

    const size_t partF = (size_t)NKG * NIMG * 2 * HW2;  // 25.7 MB
    const size_t gF    = (size_t)NIMG * 2 * HW2;        //  6.4 MB
    const size_t s0F   = (size_t)NIMG * HW2;            //  3.2 MB
    const size_t need  = (partF + s0F) * sizeof(float);

    dim3 grd(7, NIMG);
    float* s0;

    if (ws_size >= need) {
        float* part = (float*)d_ws;
        s0 = part + partF;
        dim3 grdp(7, NIMG, NKG);
        k1_partial<<<grdp, 256, 0, stream>>>(x, w1, part);
        k2f_reduce_conv2<<<grd, 448, 0, stream>>>(part, b1, w2, b2, s0);
    } else {
        float* g = (float*)d_ws;
        s0 = g + gF;
        dim3 blk(28, 16);
        k1_conv1_gelu<<<grd, blk, 0, stream>>>(x, w1, b1, g);
        k2_conv2_softmax<<<grd, blk, 0, stream>>>(g, w2, b2, s0);
    }

    const int total4 = 4 * 64 * 16 * HW * (HW / 4);
    k3_blend<<<(total4 + 255) / 256, 256, 0, stream>>>(x, s0, out, total4);
}